// Round 2
// 251.173 us; speedup vs baseline: 1.0329x; 1.0329x over previous
//
#include <hip/hip_runtime.h>
#include <stdint.h>

typedef __attribute__((ext_vector_type(8))) __bf16 bf16x8;
typedef __attribute__((ext_vector_type(4))) float f32x4;

#define DEVI __device__ __forceinline__

constexpr int Bn = 64, CIN = 64, Tn = 512, Nn = 32768, Dn = 128;
constexpr int En = 524288, ENn = En + Nn;   // 557056 edges incl self-loops
constexpr float EPSf = 1e-5f;

// ---------------- workspace layout (bytes), ~37.2 MiB (ws is >=256MB) ------
constexpr size_t OFF_XL   = 0;                        // 8 MB bf16 xl[N][128] -> y0
constexpr size_t OFF_XR   = 8388608;                  // 8 MB bf16 xr[N][128] -> y1
constexpr size_t OFF_GPAD = 16777216;                 // 64*136*512*2 = 8,912,896
constexpr size_t OFF_WRE  = 25690112;                 // 9*512*512*2 = 4,718,592
constexpr size_t OFF_WT   = 30408704;                 // 256*64*2 = 32768
constexpr size_t OFF_CNT  = 30441472;                 // 32768*4 (contig w/ stats)
constexpr size_t OFF_STAT = 30572544;
constexpr size_t OFF_SUM0 = OFF_STAT;                 // 64 f32
constexpr size_t OFF_SQ0  = OFF_STAT + 256;           // 64 f32
constexpr size_t OFF_SUM1 = OFF_STAT + 512;           // 8 replicas x 128 f32
constexpr size_t OFF_SQ1  = OFF_STAT + 4608;          // 8 replicas x 128 f32
constexpr size_t OFF_SC2  = OFF_STAT + 8704;          // 512 f32
constexpr size_t OFF_SH2  = OFF_STAT + 10752;         // 512 f32
constexpr size_t OFF_BUCK = OFF_STAT + 12800;         // 32768*64*4 = 8,388,608
constexpr size_t WS_NEED  = OFF_BUCK + 8388608;

DEVI float bf2f(unsigned short u){
  union { unsigned int u; float f; } x; x.u = ((unsigned int)u) << 16; return x.f;
}
DEVI unsigned short f2bf(float f){
  union { float f; unsigned int u; } x; x.f = f;
  unsigned int lsb = (x.u >> 16) & 1u;
  return (unsigned short)((x.u + 0x7fffu + lsb) >> 16);
}
DEVI void gl_lds16(const void* g, void* l){
  __builtin_amdgcn_global_load_lds(
      (const __attribute__((address_space(1))) unsigned int*)g,
      (__attribute__((address_space(3))) unsigned int*)l, 16, 0, 0);
}
DEVI float red32(float p){
  p += __shfl_xor(p, 1);  p += __shfl_xor(p, 2);  p += __shfl_xor(p, 4);
  p += __shfl_xor(p, 8);  p += __shfl_xor(p, 16);
  return p;
}
// rotated gpad address (bank-conflict swizzle)
DEVI size_t gpad_addr(int b, int m, int d){
  int ig = m >> 2;
  int chunk = ((m & 3) << 1) | (d >> 6);
  int est = ((d & 63) + ((ig & 7) << 3)) & 63;
  return (size_t)b * 69632 + 2048 + (size_t)ig * 512 + (chunk << 6) + est;
}

__global__ void k_mark(float* out, int n){
  int i = blockIdx.x * 256 + threadIdx.x;
  if (i < n) out[i] = 1.0f;
}

// fused: bn0 partial stats (256) | repack (516) | edge scatter->buckets (2176)
__global__ void __launch_bounds__(256) k_pre(
    const float* __restrict__ x,
    const float* __restrict__ w, const float* __restrict__ wl,
    const float* __restrict__ wr, const int* __restrict__ ei,
    float* __restrict__ sum0, float* __restrict__ sq0,
    unsigned short* __restrict__ wre, unsigned short* __restrict__ wt,
    int* __restrict__ cnt, int* __restrict__ buck){
  __shared__ float l1[256], l2[256];
  int bl = blockIdx.x, t = threadIdx.x;
  if (bl < 256){
    int c = bl >> 2, q = bl & 3;
    const float4* x4 = (const float4*)x;
    float s = 0.f, ss = 0.f;
    #pragma unroll
    for (int j = 0; j < 8; ++j){
      int idx = t + j * 256;
      int b = (q << 4) + (idx >> 7);
      int tt4 = idx & 127;
      float4 v = x4[(size_t)b * 8192 + c * 128 + tt4];
      s  += (v.x + v.y) + (v.z + v.w);
      ss += (v.x * v.x + v.y * v.y) + (v.z * v.z + v.w * v.w);
    }
    l1[t] = s; l2[t] = ss; __syncthreads();
    for (int o = 128; o > 0; o >>= 1){
      if (t < o){ l1[t] += l1[t + o]; l2[t] += l2[t + o]; }
      __syncthreads();
    }
    if (t == 0){
      atomicAdd(sum0 + c, l1[0]);
      atomicAdd(sq0 + c, l2[0]);
    }
  } else if (bl < 772){
    int b2 = bl - 256;
    if (b2 < 512){
      int to = b2;
      int rot = (to & 7) << 3;               // bank-conflict rotation
      for (int it = 0; it < 2; ++it){
        int ti = t + it * 256;
        const float* src = w + (to * 512 + ti) * 9;
        int col = (ti & ~63) | (((ti & 63) + rot) & 63);
        #pragma unroll
        for (int k = 0; k < 9; ++k)
          wre[((size_t)k * 512 + to) * 512 + col] = f2bf(src[k]);
      }
    } else {
      int q = b2 - 512;                      // 0..3
      int n = q * 64 + (t >> 2);             // 0..255
      int k0 = (t & 3) * 16;
      for (int k = k0; k < k0 + 16; ++k){
        float v = (n < 128) ? wl[k * 128 + n] : wr[k * 128 + (n - 128)];
        wt[n * 64 + k] = f2bf(v);
      }
    }
  } else {
    int e = (bl - 772) * 256 + t;            // exactly covers [0, ENn)
    int s, dst;
    if (e < En){ s = ei[e]; dst = ei[En + e]; } else { s = dst = e - En; }
    int slot = atomicAdd(cnt + dst, 1);
    if (slot < 64) buck[dst * 64 + slot] = s;
  }
}

// xlxr = bn0(x).view(N,64) @ {W_l,W_r} (MFMA); bn0 finalize inlined --------
__global__ void __launch_bounds__(256) k_xlxr(
    const float* __restrict__ x, const unsigned short* __restrict__ wt,
    const float* __restrict__ sum0, const float* __restrict__ sq0,
    const float* __restrict__ g0, const float* __restrict__ b0v,
    unsigned short* __restrict__ xl, unsigned short* __restrict__ xr){
  __shared__ unsigned short lA[128 * 64];
  __shared__ unsigned short lB[128 * 64];
  int bl = blockIdx.x, t = threadIdx.x;
  int m0 = (bl & 255) * 128;
  int nt = bl >> 8;                           // 0 -> xl, 1 -> xr
  {
    const unsigned short* gb = wt + nt * 128 * 64;
    #pragma unroll
    for (int i = 0; i < 4; ++i){
      int idx = t + i * 256;
      gl_lds16(gb + idx * 8, &lB[idx * 8]);
    }
  }
  {
    const float4* gx = (const float4*)(x + (size_t)m0 * 64);
    #pragma unroll
    for (int i = 0; i < 8; ++i){
      int idx = t + i * 256;
      float4 v = gx[idx];
      int row = idx >> 4;
      int ch = ((m0 + row) >> 3) & 63;
      float mean = sum0[ch] * (1.f / 32768.f);
      float var  = sq0[ch] * (1.f / 32768.f) - mean * mean;
      float sc = rsqrtf(var + EPSf) * g0[ch];
      float sh = b0v[ch] - mean * sc;
      unsigned int p0 = (unsigned int)f2bf(v.x * sc + sh) | ((unsigned int)f2bf(v.y * sc + sh) << 16);
      unsigned int p1 = (unsigned int)f2bf(v.z * sc + sh) | ((unsigned int)f2bf(v.w * sc + sh) << 16);
      *(uint2*)&lA[idx * 4] = make_uint2(p0, p1);
    }
  }
  __syncthreads();
  int w = t >> 6, lane = t & 63;
  int wm = (w & 1) * 64, wn = (w >> 1) * 64;
  int lrow = lane & 15, quad = lane >> 4;
  const f32x4 fz = {0.f, 0.f, 0.f, 0.f};
  f32x4 acc[4][4];
  #pragma unroll
  for (int i = 0; i < 4; ++i)
    #pragma unroll
    for (int j = 0; j < 4; ++j) acc[i][j] = fz;
  #pragma unroll
  for (int kk = 0; kk < 2; ++kk){
    bf16x8 a[4], bfr[4];
    #pragma unroll
    for (int i = 0; i < 4; ++i){
      a[i]   = *(const bf16x8*)&lA[(wm + i * 16 + lrow) * 64 + kk * 32 + quad * 8];
      bfr[i] = *(const bf16x8*)&lB[(wn + i * 16 + lrow) * 64 + kk * 32 + quad * 8];
    }
    #pragma unroll
    for (int i = 0; i < 4; ++i)
      #pragma unroll
      for (int j = 0; j < 4; ++j)
        acc[i][j] = __builtin_amdgcn_mfma_f32_16x16x32_bf16(a[i], bfr[j], acc[i][j], 0, 0, 0);
  }
  unsigned short* outb = nt ? xr : xl;
  #pragma unroll
  for (int i = 0; i < 4; ++i)
    #pragma unroll
    for (int j = 0; j < 4; ++j)
      #pragma unroll
      for (int r = 0; r < 4; ++r){
        int row = m0 + wm + i * 16 + quad * 4 + r;
        int col = wn + j * 16 + lrow;
        outb[row * 128 + col] = f2bf(acc[i][j][r]);
      }
}

// -- GATv2: ONE dst per wave (8192 blocks), x4 edge unroll, fused BN1 stats -
__global__ void __launch_bounds__(256) k_gat(
    const unsigned short* __restrict__ xl, const unsigned short* __restrict__ xr,
    const float* __restrict__ att,
    const int* __restrict__ cnt, const int* __restrict__ buck,
    unsigned short* __restrict__ gpad,
    float* __restrict__ sum1, float* __restrict__ sq1){
  __shared__ float S[4][128], Q[4][128];
  int t = threadIdx.x;
  int wv = t >> 6, lane = t & 63;
  int dst = blockIdx.x * 4 + wv;
  float2 pa = *(const float2*)(att + (lane << 1));
  float a0 = pa.x, a1 = pa.y;
  unsigned int pr = *(const unsigned int*)(xr + (size_t)dst * 128 + (lane << 1));
  float r0 = bf2f((unsigned short)(pr & 0xffffu)), r1 = bf2f((unsigned short)(pr >> 16));
  const int* bk = buck + dst * 64;
  int deg = cnt[dst]; deg = deg > 64 ? 64 : deg;
  float z = 0.f, ac0 = 0.f, ac1 = 0.f;
  int i = 0;
  for (; i + 4 <= deg; i += 4){
    int s0 = bk[i], s1 = bk[i + 1], s2 = bk[i + 2], s3 = bk[i + 3];
    unsigned int px0 = *(const unsigned int*)(xl + (size_t)s0 * 128 + (lane << 1));
    unsigned int px1 = *(const unsigned int*)(xl + (size_t)s1 * 128 + (lane << 1));
    unsigned int px2 = *(const unsigned int*)(xl + (size_t)s2 * 128 + (lane << 1));
    unsigned int px3 = *(const unsigned int*)(xl + (size_t)s3 * 128 + (lane << 1));
    float x00 = bf2f((unsigned short)(px0 & 0xffffu)), x01 = bf2f((unsigned short)(px0 >> 16));
    float x10 = bf2f((unsigned short)(px1 & 0xffffu)), x11 = bf2f((unsigned short)(px1 >> 16));
    float x20 = bf2f((unsigned short)(px2 & 0xffffu)), x21 = bf2f((unsigned short)(px2 >> 16));
    float x30 = bf2f((unsigned short)(px3 & 0xffffu)), x31 = bf2f((unsigned short)(px3 >> 16));
    float h, p0, p1, p2, p3;
    h = x00 + r0; h = fmaxf(h, 0.2f * h); p0 = h * a0;
    h = x01 + r1; h = fmaxf(h, 0.2f * h); p0 += h * a1;
    h = x10 + r0; h = fmaxf(h, 0.2f * h); p1 = h * a0;
    h = x11 + r1; h = fmaxf(h, 0.2f * h); p1 += h * a1;
    h = x20 + r0; h = fmaxf(h, 0.2f * h); p2 = h * a0;
    h = x21 + r1; h = fmaxf(h, 0.2f * h); p2 += h * a1;
    h = x30 + r0; h = fmaxf(h, 0.2f * h); p3 = h * a0;
    h = x31 + r1; h = fmaxf(h, 0.2f * h); p3 += h * a1;
    p0 += __shfl_xor(p0, 1);  p1 += __shfl_xor(p1, 1);
    p2 += __shfl_xor(p2, 1);  p3 += __shfl_xor(p3, 1);
    p0 += __shfl_xor(p0, 2);  p1 += __shfl_xor(p1, 2);
    p2 += __shfl_xor(p2, 2);  p3 += __shfl_xor(p3, 2);
    p0 += __shfl_xor(p0, 4);  p1 += __shfl_xor(p1, 4);
    p2 += __shfl_xor(p2, 4);  p3 += __shfl_xor(p3, 4);
    p0 += __shfl_xor(p0, 8);  p1 += __shfl_xor(p1, 8);
    p2 += __shfl_xor(p2, 8);  p3 += __shfl_xor(p3, 8);
    p0 += __shfl_xor(p0, 16); p1 += __shfl_xor(p1, 16);
    p2 += __shfl_xor(p2, 16); p3 += __shfl_xor(p3, 16);
    float w0 = __expf(p0), w1 = __expf(p1), w2 = __expf(p2), w3 = __expf(p3);
    z += (w0 + w1) + (w2 + w3);
    ac0 += w0 * x00; ac0 += w1 * x10; ac0 += w2 * x20; ac0 += w3 * x30;
    ac1 += w0 * x01; ac1 += w1 * x11; ac1 += w2 * x21; ac1 += w3 * x31;
  }
  for (; i < deg; ++i){
    int s = bk[i];
    unsigned int px = *(const unsigned int*)(xl + (size_t)s * 128 + (lane << 1));
    float x0 = bf2f((unsigned short)(px & 0xffffu)), x1 = bf2f((unsigned short)(px >> 16));
    float h0 = x0 + r0; h0 = fmaxf(h0, 0.2f * h0);
    float h1 = x1 + r1; h1 = fmaxf(h1, 0.2f * h1);
    float p = red32(h0 * a0 + h1 * a1);
    float w = __expf(p);
    z += w; ac0 += w * x0; ac1 += w * x1;
  }
  float inv = (z > 0.f) ? 1.f / z : 0.f;
  float o0 = ac0 * inv, o1 = ac1 * inv;
  size_t off = gpad_addr(dst >> 9, dst & 511, lane << 1);
  *(unsigned int*)(gpad + off) =
      (unsigned int)f2bf(o0) | ((unsigned int)f2bf(o1) << 16);
  // fused BN1 partial stats: block-reduce 4 dst, atomics into 1-of-8 replicas
  S[wv][lane * 2] = o0; S[wv][lane * 2 + 1] = o1;
  Q[wv][lane * 2] = o0 * o0; Q[wv][lane * 2 + 1] = o1 * o1;
  __syncthreads();
  int rep = (blockIdx.x & 7) << 7;
  if (t < 128){
    atomicAdd(sum1 + rep + t, (S[0][t] + S[1][t]) + (S[2][t] + S[3][t]));
  } else {
    int c = t - 128;
    atomicAdd(sq1 + rep + c, (Q[0][c] + Q[1][c]) + (Q[2][c] + Q[3][c]));
  }
}

// relu(bn1) in place on rotated gpad (finalize over 8 replicas) + pad zeroing
__global__ void __launch_bounds__(256) k_bn1_apply(
    unsigned short* __restrict__ gpad,
    const float* __restrict__ sums, const float* __restrict__ sumsq,
    const float* __restrict__ g, const float* __restrict__ bb){
  int bl = blockIdx.x, t = threadIdx.x;
  if (bl >= 4096){
    int idx = (bl - 4096) * 256 + t;           // 0..65535
    int b = idx >> 10, r = idx & 1023;
    int region = r >> 9, rp = r & 511;
    size_t off = (size_t)b * 69632 + (region ? 67584 : 0) + rp * 4;
    *(uint2*)(gpad + off) = make_uint2(0u, 0u);
    return;
  }
  int gi = bl * 256 + t;
  int f0 = gi * 4;
  int b = f0 >> 16, q = f0 & 65535;
  int m = q >> 7, d0 = q & 127;
  float sc[4], sh[4];
  #pragma unroll
  for (int j = 0; j < 4; ++j){
    int d = d0 + j;
    float s = 0.f, ssq = 0.f;
    #pragma unroll
    for (int r = 0; r < 8; ++r){
      s   += sums[(r << 7) + d];
      ssq += sumsq[(r << 7) + d];
    }
    float mean = s / 32768.f;
    float var  = ssq / 32768.f - mean * mean;
    float rs = rsqrtf(var + EPSf) * g[d];
    sc[j] = rs; sh[j] = bb[d] - mean * rs;
  }
  unsigned short* gp = gpad + gpad_addr(b, m, d0);
  uint2 v = *(const uint2*)gp;
  float o0 = fmaxf(0.f, bf2f((unsigned short)(v.x & 0xffffu)) * sc[0] + sh[0]);
  float o1 = fmaxf(0.f, bf2f((unsigned short)(v.x >> 16))     * sc[1] + sh[1]);
  float o2 = fmaxf(0.f, bf2f((unsigned short)(v.y & 0xffffu)) * sc[2] + sh[2]);
  float o3 = fmaxf(0.f, bf2f((unsigned short)(v.y >> 16))     * sc[3] + sh[3]);
  unsigned int p0 = (unsigned int)f2bf(o0) | ((unsigned int)f2bf(o1) << 16);
  unsigned int p1 = (unsigned int)f2bf(o2) | ((unsigned int)f2bf(o3) << 16);
  *(uint2*)gp = make_uint2(p0, p1);
}

// -- conv implicit GEMM, split-K=2, BK=64, LDS double-buffer ---------------
// Grid is a flat 512 with an XCD-aware bijective swizzle (512 % 8 == 0):
//   hw XCD = id & 7 (round-robin dispatch), u = id >> 3 (temporal order)
//   XCD i owns: z = i&1, b in [16*(i>>1), 16*(i>>1)+16), all 4 to0 tiles.
//   u order = to0 fastest, then b: the 4 wre A-slices for this (to0 set,
//   K-half) stay L2-resident (~2.4 MB) while gpad[b] streams (139 KB each).
//   gpad is then fetched exactly once chip-wide; wre halves 4x each
//   (ideal FETCH ~28 MB vs measured 62 MB with the unswizzled dim3 grid).
__global__ void __launch_bounds__(256) k_conv(
    const unsigned short* __restrict__ wre,   // [9][512][512] rotated
    const unsigned short* __restrict__ gpad,  // [64][136][512] rotated
    unsigned short* __restrict__ y0, unsigned short* __restrict__ y1){
  __shared__ unsigned short lA[2][128 * 64];
  __shared__ unsigned short lB[2][128 * 64];
  int t = threadIdx.x;
  int id  = blockIdx.x;
  int xcd = id & 7, u = id >> 3;
  int z   = xcd & 1;
  int b   = (xcd >> 1) * 16 + (u >> 2);
  int to0 = (u & 3) * 128;
  int w = t >> 6, lane = t & 63;
  int wm = (w & 1) * 64, wn = (w >> 1) * 64;
  int lrow = lane & 15, quad = lane >> 4;
  const f32x4 fz = {0.f, 0.f, 0.f, 0.f};
  f32x4 acc[4][4];
  #pragma unroll
  for (int i = 0; i < 4; ++i)
    #pragma unroll
    for (int j = 0; j < 4; ++j) acc[i][j] = fz;
  const unsigned short* gbb = gpad + (size_t)b * 69632;
  int ra = lrow & 7;
  int og[4], ol[4];
  #pragma unroll
  for (int i = 0; i < 4; ++i){
    int idx = t + i * 256;
    og[i] = (idx >> 3) * 512 + (idx & 7) * 8;
    ol[i] = idx * 8;
  }
  int s0 = z * 36;
  {
    int k = s0 >> 3, c = s0 & 7;
    const unsigned short* ga = wre + ((size_t)k * 512 + to0) * 512 + c * 64;
    const unsigned short* gB = gbb + k * 512 + c * 64;
    #pragma unroll
    for (int i = 0; i < 4; ++i){
      gl_lds16(ga + og[i], &lA[0][ol[i]]);
      gl_lds16(gB + og[i], &lB[0][ol[i]]);
    }
  }
  __syncthreads();
  for (int it = 0; it < 36; ++it){
    int s = s0 + it;
    if (it < 35){
      int sn = s + 1;
      int k = sn >> 3, c = sn & 7;
      const unsigned short* ga = wre + ((size_t)k * 512 + to0) * 512 + c * 64;
      const unsigned short* gB = gbb + k * 512 + c * 64;
      int nb = (it + 1) & 1;
      #pragma unroll
      for (int i = 0; i < 4; ++i){
        gl_lds16(ga + og[i], &lA[nb][ol[i]]);
        gl_lds16(gB + og[i], &lB[nb][ol[i]]);
      }
    }
    int cb = it & 1;
    const unsigned short* la = lA[cb];
    const unsigned short* lb = lB[cb];
    int k = s >> 3;
    int rb = (k + 4 + lrow) & 7;
    #pragma unroll
    for (int kk = 0; kk < 2; ++kk){
      int colA = ((kk << 5) + (quad << 3) + (ra << 3)) & 63;
      int colB = ((kk << 5) + (quad << 3) + (rb << 3)) & 63;
      bf16x8 a[4], bfr[4];
      #pragma unroll
      for (int i = 0; i < 4; ++i){
        a[i]   = *(const bf16x8*)&la[(wm + i * 16 + lrow) * 64 + colA];
        bfr[i] = *(const bf16x8*)&lb[(wn + i * 16 + lrow) * 64 + colB];
      }
      #pragma unroll
      for (int i = 0; i < 4; ++i)
        #pragma unroll
        for (int j = 0; j < 4; ++j)
          acc[i][j] = __builtin_amdgcn_mfma_f32_16x16x32_bf16(a[i], bfr[j], acc[i][j], 0, 0, 0);
    }
    __syncthreads();
  }
  unsigned short* yo = z ? y1 : y0;
  #pragma unroll
  for (int i = 0; i < 4; ++i)
    #pragma unroll
    for (int j = 0; j < 4; ++j)
      #pragma unroll
      for (int r = 0; r < 4; ++r){
        int to = to0 + wm + i * 16 + quad * 4 + r;
        int p  = wn + j * 16 + lrow;
        yo[((size_t)b * 512 + to) * 128 + p] = f2bf(acc[i][j][r]);
      }
}

// ---------------- BN2 stats (block per out-channel) ----------------
__global__ void k_bn2_stats(const unsigned short* __restrict__ y0,
                            const unsigned short* __restrict__ y1,
                            const float* __restrict__ g, const float* __restrict__ bb,
                            float* __restrict__ scale, float* __restrict__ shift){
  int to = blockIdx.x, t = threadIdx.x;
  int p = t & 127, b0 = t >> 7;
  float s = 0.f, ss = 0.f;
  for (int b = b0; b < 64; b += 2){
    size_t idx = ((size_t)b * 512 + to) * 128 + p;
    float v = bf2f(y0[idx]) + bf2f(y1[idx]);
    s += v; ss += v * v;
  }
  __shared__ float l1[256], l2[256];
  l1[t] = s; l2[t] = ss; __syncthreads();
  for (int o = 128; o > 0; o >>= 1){
    if (t < o){ l1[t] += l1[t + o]; l2[t] += l2[t + o]; }
    __syncthreads();
  }
  if (t == 0){
    float mean = l1[0] / 8192.f;
    float var  = l2[0] / 8192.f - mean * mean;
    float rs = rsqrtf(var + EPSf) * g[to];
    scale[to] = rs;
    shift[to] = bb[to] - mean * rs;
  }
}

// -------- final: out = residual(from rotated gpad) + transpose(relu(bn2(y)))
__global__ void __launch_bounds__(256) k_final(
    const unsigned short* __restrict__ y0, const unsigned short* __restrict__ y1,
    const unsigned short* __restrict__ gpad,
    const float* __restrict__ scale, const float* __restrict__ shift,
    float* __restrict__ out){
  __shared__ float lt[32][33];
  int jt = blockIdx.x, it = blockIdx.y, b = blockIdx.z;
  int j0 = jt * 32, i0 = it * 32;
  int t = threadIdx.x;
  #pragma unroll
  for (int q = 0; q < 4; ++q){
    int li = t + q * 256;
    int r = li >> 5, cc = li & 31;
    int j = j0 + r;
    size_t idx = ((size_t)b * 512 + j) * 128 + i0 + cc;
    float v = bf2f(y0[idx]) + bf2f(y1[idx]);
    lt[r][cc] = fmaxf(0.f, v * scale[j] + shift[j]);
  }
  __syncthreads();
  const unsigned short* gbb = gpad + (size_t)b * 69632 + 2048;
  #pragma unroll
  for (int q = 0; q < 4; ++q){
    int li = t + q * 256;
    int ii = li >> 5, jj = li & 31;
    int i = i0 + ii, j = j0 + jj;
    int est = ((j & 63) + ((i & 7) << 3)) & 63;
    float res = bf2f(gbb[(size_t)i * 512 + ((j >> 6) << 6) + est]);
    size_t o = (size_t)b * 65536 + (size_t)i * 512 + j;
    out[o] = res + lt[jj][ii];
  }
}

extern "C" void kernel_launch(void* const* d_in, const int* in_sizes, int n_in,
                              void* d_out, int out_size, void* d_ws, size_t ws_size,
                              hipStream_t stream){
  const float* x     = (const float*)d_in[0];
  const int*   ei    = (const int*)d_in[1];
  const float* bn0g  = (const float*)d_in[2];
  const float* bn0b  = (const float*)d_in[3];
  const float* Wl    = (const float*)d_in[4];
  const float* Wr    = (const float*)d_in[5];
  const float* att   = (const float*)d_in[6];
  // d_in[7] gat_b cancels in BN1; d_in[11] conv_b cancels in BN2
  const float* bn1g  = (const float*)d_in[8];
  const float* bn1b  = (const float*)d_in[9];
  const float* convw = (const float*)d_in[10];
  const float* bn2g  = (const float*)d_in[12];
  const float* bn2b  = (const float*)d_in[13];
  float* out = (float*)d_out;

  if (ws_size < WS_NEED){
    k_mark<<<(out_size + 255) / 256, 256, 0, stream>>>(out, out_size);
    return;
  }
  char* ws = (char*)d_ws;
  unsigned short* xl   = (unsigned short*)(ws + OFF_XL);
  unsigned short* xr   = (unsigned short*)(ws + OFF_XR);
  unsigned short* y0   = (unsigned short*)(ws + OFF_XL);   // alias: xl dead
  unsigned short* y1   = (unsigned short*)(ws + OFF_XR);   // alias: xr dead
  unsigned short* gpad = (unsigned short*)(ws + OFF_GPAD);
  unsigned short* wre  = (unsigned short*)(ws + OFF_WRE);
  unsigned short* wt   = (unsigned short*)(ws + OFF_WT);
  int*            cnt  = (int*)(ws + OFF_CNT);
  int*            buck = (int*)(ws + OFF_BUCK);
  float*          sum0 = (float*)(ws + OFF_SUM0);
  float*          sq0  = (float*)(ws + OFF_SQ0);
  float*          sum1 = (float*)(ws + OFF_SUM1);
  float*          sq1  = (float*)(ws + OFF_SQ1);
  float*          sc2  = (float*)(ws + OFF_SC2);
  float*          sh2  = (float*)(ws + OFF_SH2);

  // single memset: cnt (128 KB) + sum0|sq0|sum1x8|sq1x8 (8.7 KB), contiguous
  hipMemsetAsync(cnt, 0, 139776, stream);

  k_pre<<<2948, 256, 0, stream>>>(x, convw, Wl, Wr, ei, sum0, sq0, wre, wt, cnt, buck);
  k_xlxr<<<512, 256, 0, stream>>>(x, wt, sum0, sq0, bn0g, bn0b, xl, xr);
  k_gat<<<8192, 256, 0, stream>>>(xl, xr, att, cnt, buck, gpad, sum1, sq1);
  k_bn1_apply<<<4352, 256, 0, stream>>>(gpad, sum1, sq1, bn1g, bn1b);
  k_conv<<<512, 256, 0, stream>>>(wre, gpad, y0, y1);
  k_bn2_stats<<<512, 256, 0, stream>>>(y0, y1, bn2g, bn2b, sc2, sh2);
  k_final<<<dim3(16, 4, 64), 256, 0, stream>>>(y0, y1, gpad, sc2, sh2, out);

  (void)in_sizes; (void)n_in;
}